// Round 7
// baseline (585.727 us; speedup 1.0000x reference)
//
#include <hip/hip_runtime.h>
#include <stdint.h>

#define SEQ  2048
#define DIMC 256
#define HID  512
#define NH   8
#define DH   64

typedef __attribute__((ext_vector_type(8))) short bf16x8;
typedef __attribute__((ext_vector_type(4))) float f32x4;
typedef __attribute__((ext_vector_type(16))) float f32x16;
typedef __attribute__((ext_vector_type(2))) unsigned uint2v;
typedef __attribute__((address_space(1))) const uint32_t guint_t;
typedef __attribute__((address_space(3))) uint32_t luint_t;

__device__ __forceinline__ void gld16(const void* g, void* l) {
  __builtin_amdgcn_global_load_lds((guint_t*)g, (luint_t*)l, 16, 0, 0);
}

__device__ __forceinline__ uint32_t fbits(float f) {
  union { float f; uint32_t u; } v; v.f = f; return v.u;
}
__device__ __forceinline__ unsigned short f2bf(float f) {
  uint32_t u = fbits(f);
  return (unsigned short)((u + 0x7FFFu + ((u >> 16) & 1u)) >> 16);
}
// pack two fp32 (raw bits) -> (bf16,bf16) dword, round-half-up
__device__ __forceinline__ uint32_t pku(uint32_t u0, uint32_t u1) {
  return __builtin_amdgcn_perm(u1 + 0x8000u, u0 + 0x8000u, 0x07060302u);
}

// exchange hi 32 lanes of a with lo 32 lanes of b
__device__ __forceinline__ void swap32(uint32_t& a, uint32_t& b) {
#if __has_builtin(__builtin_amdgcn_permlane32_swap)
  uint2v r = __builtin_amdgcn_permlane32_swap(a, b, false, false);
  a = r[0]; b = r[1];
#else
  uint32_t aw = __shfl_xor(a, 32);
  uint32_t bw = __shfl_xor(b, 32);
  bool lo = (threadIdx.x & 32) == 0;
  uint32_t an = lo ? a : bw;
  uint32_t bn = lo ? aw : b;
  a = an; b = bn;
#endif
}

// ---------------------------------------------------------------------------
// prep: w_qkv -> bf16 (Q rows pre-scaled by SCALE*log2e), w_out -> bf16,
//       x [b][i][n] fp32 -> xT [b][n][i] bf16     (R5 version, verbatim)
// ---------------------------------------------------------------------------
__global__ __launch_bounds__(256) void prep_kernel(
    const float* __restrict__ x, const float* __restrict__ wqkv,
    const float* __restrict__ wout,
    unsigned short* __restrict__ wqkv_b, unsigned short* __restrict__ wout_b,
    unsigned short* __restrict__ xT) {
  __shared__ float tile[64][65];
  int blk = blockIdx.x;
  int t = threadIdx.x;
  if (blk < 384) {
    int idx = blk * 1024 + t * 4;
    float4 v = *(const float4*)(wqkv + idx);
    float s = ((idx >> 8) < HID) ? 0.18033688011112042f : 1.0f;  // 0.125*log2(e)
    ushort4 o;
    o.x = f2bf(v.x * s); o.y = f2bf(v.y * s);
    o.z = f2bf(v.z * s); o.w = f2bf(v.w * s);
    *(ushort4*)(wqkv_b + idx) = o;
    return;
  }
  if (blk < 512) {
    int idx = (blk - 384) * 1024 + t * 4;
    float4 v = *(const float4*)(wout + idx);
    ushort4 o;
    o.x = f2bf(v.x); o.y = f2bf(v.y); o.z = f2bf(v.z); o.w = f2bf(v.w);
    *(ushort4*)(wout_b + idx) = o;
    return;
  }
  int tid = blk - 512;
  int b  = tid >> 7;
  int r  = tid & 127;
  int i0 = (r >> 5) * 64;
  int n0 = (r & 31) * 64;
  const float* xb = x + (size_t)b * DIMC * SEQ;
  int tn = t & 15, ti = t >> 4;
#pragma unroll
  for (int j = 0; j < 4; j++) {
    int il = ti + j * 16;
    float4 v = *(const float4*)(xb + (size_t)(i0 + il) * SEQ + n0 + tn * 4);
    tile[il][tn*4+0] = v.x; tile[il][tn*4+1] = v.y;
    tile[il][tn*4+2] = v.z; tile[il][tn*4+3] = v.w;
  }
  __syncthreads();
  unsigned short* xTb = xT + (size_t)b * SEQ * DIMC;
#pragma unroll
  for (int j = 0; j < 4; j++) {
    int nl = ti + j * 16;
    int i4 = tn * 4;
    uint2 pk;
    pk.x = (uint32_t)f2bf(tile[i4+0][nl]) | ((uint32_t)f2bf(tile[i4+1][nl]) << 16);
    pk.y = (uint32_t)f2bf(tile[i4+2][nl]) | ((uint32_t)f2bf(tile[i4+3][nl]) << 16);
    *(uint2*)(xTb + (size_t)(n0 + nl) * DIMC + i0 + i4) = pk;
  }
}

// ---------------------------------------------------------------------------
// qkv_gemm: 128x128 tile, BK=64, gld16 swizzled staging   (R5 version)
// ---------------------------------------------------------------------------
__global__ __launch_bounds__(256, 2) void qkv_gemm(
    const unsigned short* __restrict__ wq, const unsigned short* __restrict__ xT,
    unsigned short* __restrict__ Qs, unsigned short* __restrict__ Ks,
    unsigned short* __restrict__ Vt) {
  __shared__ unsigned short lds[17408];
  unsigned short* la = lds;
  unsigned short* lb = lds + 8192;
  int o0 = blockIdx.x * 128;
  int n0 = blockIdx.y * 128;
  int b  = blockIdx.z;
  int t  = threadIdx.x;
  int wv = t >> 6, l = t & 63, l15 = l & 15, q = l >> 4;
  int wm = (wv & 1) * 64, wn = (wv >> 1) * 64;
  f32x4 acc[4][4];
#pragma unroll
  for (int i = 0; i < 4; i++)
#pragma unroll
    for (int j = 0; j < 4; j++) acc[i][j] = (f32x4){0.f, 0.f, 0.f, 0.f};
  const unsigned short* Ag = wq + (size_t)o0 * DIMC;
  const unsigned short* Bg = xT + ((size_t)b * SEQ + n0) * DIMC;
  int lrow8 = l >> 3, lcol = l & 7;
  for (int kk = 0; kk < 4; kk++) {
    int k0 = kk * 64;
    __syncthreads();
#pragma unroll
    for (int c0 = 0; c0 < 4; c0++) {
      int c = wv * 4 + c0;
      int row = c * 8 + lrow8;
      int sg = lcol ^ (row & 7);
      gld16(Ag + (size_t)row * DIMC + k0 + sg * 8, la + c * 512);
      gld16(Bg + (size_t)row * DIMC + k0 + sg * 8, lb + c * 512);
    }
    __syncthreads();
#pragma unroll
    for (int kh = 0; kh < 2; kh++) {
      bf16x8 af[4], bfr[4];
#pragma unroll
      for (int mt = 0; mt < 4; mt++) {
        int row = wm + mt*16 + l15;
        af[mt] = *(const bf16x8*)(la + row*64 + ((kh*4 + q) ^ (row & 7)) * 8);
      }
#pragma unroll
      for (int nt = 0; nt < 4; nt++) {
        int row = wn + nt*16 + l15;
        bfr[nt] = *(const bf16x8*)(lb + row*64 + ((kh*4 + q) ^ (row & 7)) * 8);
      }
#pragma unroll
      for (int mt = 0; mt < 4; mt++)
#pragma unroll
        for (int nt = 0; nt < 4; nt++)
          acc[mt][nt] = __builtin_amdgcn_mfma_f32_16x16x32_bf16(af[mt], bfr[nt], acc[mt][nt], 0, 0, 0);
    }
  }
  __syncthreads();
  int seg3 = o0 >> 9;
  int h0   = (o0 & 511) >> 6;
  if (seg3 == 2) {
#pragma unroll
    for (int mt = 0; mt < 4; mt++)
#pragma unroll
      for (int nt = 0; nt < 4; nt++)
#pragma unroll
        for (int r = 0; r < 4; r++) {
          int ol = wm + mt * 16 + q * 4 + r;
          int h = h0 + (ol >> 6), d = ol & 63;
          int n = n0 + wn + nt * 16 + l15;
          Vt[(((size_t)b * NH + h) * DH + d) * SEQ + n] = f2bf(acc[mt][nt][r]);
        }
  } else {
    unsigned short* dst = (seg3 == 0) ? Qs : Ks;
#pragma unroll
    for (int mt = 0; mt < 4; mt++)
#pragma unroll
      for (int nt = 0; nt < 4; nt++)
#pragma unroll
        for (int r = 0; r < 4; r++) {
          int ol = wm + mt * 16 + q * 4 + r;
          int nn = wn + nt * 16 + l15;
          lds[nn * 136 + ol] = f2bf(acc[mt][nt][r]);
        }
    __syncthreads();
#pragma unroll
    for (int i = 0; i < 8; i++) {
      int idx = i * 256 + t;
      int nn  = idx >> 4;
      int olb = (idx & 15) * 8;
      uint4 v = *(const uint4*)(lds + nn * 136 + olb);
      int h = h0 + (olb >> 6), d = olb & 63;
      *(uint4*)(dst + (((size_t)b * NH + h) * SEQ + n0 + nn) * DH + d) = v;
    }
  }
}

// ---------------------------------------------------------------------------
// attn: TLP-first. Grid 1024 blocks x 256 thr (4 waves) = 4 blocks/CU,
// 4 waves/SIMD (VGPR capped 128). Block = 64 queries; wave cg owns keys
// [cg*512, cg*512+512). K/V frags straight from global (L2-hot tiles) --
// ZERO LDS and ZERO barriers in the K-loop. Register P-transform.
// Additive partials -> 4-barrier LDS tree-combine + normalize.
// ---------------------------------------------------------------------------
__global__ __launch_bounds__(256, 4) void attn_kernel(
    const unsigned short* __restrict__ Qs, const unsigned short* __restrict__ Ks,
    const unsigned short* __restrict__ Vt, unsigned short* __restrict__ AO) {
  __shared__ float Ocf[8192];     // two 16 KB combine buffers
  __shared__ float Lc[256];       // [cg][64 q] row sums
  int n0 = blockIdx.x * 64;
  int bh = blockIdx.y;
  int b = bh >> 3, h = bh & 7;
  int t = threadIdx.x;
  int cg = t >> 6, l = t & 63, l31 = l & 31, lh = l >> 5;
  // Q B-frags, once
  const unsigned short* Qg = Qs + ((size_t)bh * SEQ + n0) * DH;
  bf16x8 qb[2][4];
#pragma unroll
  for (int qt = 0; qt < 2; qt++)
#pragma unroll
    for (int kc = 0; kc < 4; kc++)
      qb[qt][kc] = *(const bf16x8*)(Qg + (qt*32 + l31) * DH + kc*16 + lh*8);
  f32x16 oacc[2][2];
  float lrowp[2] = {0.f, 0.f};
#pragma unroll
  for (int qt = 0; qt < 2; qt++)
#pragma unroll
    for (int dt = 0; dt < 2; dt++)
#pragma unroll
      for (int r = 0; r < 16; r++) oacc[qt][dt][r] = 0.f;
  const unsigned short* Kg = Ks + ((size_t)bh * SEQ + cg * 512) * DH;
  const unsigned short* Vg = Vt + (size_t)bh * DH * SEQ + cg * 512;
  for (int it = 0; it < 16; it++) {
    int kb = it * 32;
    // V B-frags early (independent; hide latency under QK+exp)
    bf16x8 vf[2][2];
#pragma unroll
    for (int kc2 = 0; kc2 < 2; kc2++)
#pragma unroll
      for (int dt = 0; dt < 2; dt++)
        vf[kc2][dt] = *(const bf16x8*)(Vg + (size_t)(dt*32 + l31) * SEQ + kb + kc2*16 + lh*8);
    // S^T = K Q^T : D[m=key][n=query=l31]
    f32x16 st[2];
#pragma unroll
    for (int qt = 0; qt < 2; qt++)
#pragma unroll
      for (int r = 0; r < 16; r++) st[qt][r] = 0.f;
#pragma unroll
    for (int kc = 0; kc < 4; kc++) {
      bf16x8 kf = *(const bf16x8*)(Kg + (size_t)(kb + l31) * DH + kc*16 + lh*8);
      st[0] = __builtin_amdgcn_mfma_f32_32x32x16_bf16(kf, qb[0][kc], st[0], 0, 0, 0);
      st[1] = __builtin_amdgcn_mfma_f32_32x32x16_bf16(kf, qb[1][kc], st[1], 0, 0, 0);
    }
#pragma unroll
    for (int qt = 0; qt < 2; qt++) {
      float p[16];
      float s0 = 0.f;
#pragma unroll
      for (int r = 0; r < 16; r++) { p[r] = __builtin_amdgcn_exp2f(st[qt][r]); s0 += p[r]; }
      lrowp[qt] += s0;
      bf16x8 af[2];
#pragma unroll
      for (int hf = 0; hf < 2; hf++) {
        uint32_t xs[4], ys[4];
#pragma unroll
        for (int j = 0; j < 4; j++) {
          xs[j] = fbits(p[hf*8 + j]);
          ys[j] = fbits(p[hf*8 + 4 + j]);
          swap32(xs[j], ys[j]);
        }
        union { uint32_t u[4]; bf16x8 v; } cv;
        cv.u[0] = pku(xs[0], xs[1]);
        cv.u[1] = pku(xs[2], xs[3]);
        cv.u[2] = pku(ys[0], ys[1]);
        cv.u[3] = pku(ys[2], ys[3]);
        af[hf] = cv.v;
      }
#pragma unroll
      for (int kc2 = 0; kc2 < 2; kc2++)
#pragma unroll
        for (int dt = 0; dt < 2; dt++)
          oacc[qt][dt] = __builtin_amdgcn_mfma_f32_32x32x16_bf16(af[kc2], vf[kc2][dt], oacc[qt][dt], 0, 0, 0);
    }
  }
  // ---- row sums: regs+lh cover all 32 keys of each group ----
#pragma unroll
  for (int qt = 0; qt < 2; qt++) {
    float v = lrowp[qt];
    v += __shfl_xor(v, 32);
    if (l < 32) Lc[cg * 64 + qt * 32 + l31] = v;
  }
  // ---- 4-partial additive tree combine in LDS ----
  auto dump = [&](float* R) {
#pragma unroll
    for (int qt = 0; qt < 2; qt++)
#pragma unroll
      for (int dt = 0; dt < 2; dt++)
#pragma unroll
        for (int rr = 0; rr < 4; rr++)
          *(f32x4*)(R + ((qt*2+dt)*4 + rr) * 256 + l * 4) =
            (f32x4){oacc[qt][dt][rr*4+0], oacc[qt][dt][rr*4+1],
                    oacc[qt][dt][rr*4+2], oacc[qt][dt][rr*4+3]};
  };
  auto addin = [&](const float* R) {
#pragma unroll
    for (int qt = 0; qt < 2; qt++)
#pragma unroll
      for (int dt = 0; dt < 2; dt++)
#pragma unroll
        for (int rr = 0; rr < 4; rr++) {
          f32x4 v = *(const f32x4*)(R + ((qt*2+dt)*4 + rr) * 256 + l * 4);
          oacc[qt][dt][rr*4+0] += v[0]; oacc[qt][dt][rr*4+1] += v[1];
          oacc[qt][dt][rr*4+2] += v[2]; oacc[qt][dt][rr*4+3] += v[3];
        }
  };
  if (cg == 1) dump(Ocf);
  if (cg == 3) dump(Ocf + 4096);
  __syncthreads();
  if (cg == 0) addin(Ocf);
  if (cg == 2) addin(Ocf + 4096);
  __syncthreads();
  if (cg == 2) dump(Ocf);
  __syncthreads();
  if (cg == 0) {
    addin(Ocf);
    unsigned short* AOb = AO + (size_t)b * SEQ * HID + h * DH;
#pragma unroll
    for (int qt = 0; qt < 2; qt++)
#pragma unroll
      for (int r = 0; r < 16; r++) {
        int qrow = qt*32 + (r & 3) + 8*(r >> 2) + 4*lh;
        float lsum = Lc[qrow&63 ? qrow : qrow] ;  // placate compiler
        lsum = Lc[(qrow & 31) + (qt*32)] ;
        lsum = Lc[qrow] + Lc[64 + qrow] + Lc[128 + qrow] + Lc[192 + qrow];
        float inv = __builtin_amdgcn_rcpf(lsum);
        int n = n0 + qrow;
#pragma unroll
        for (int dt = 0; dt < 2; dt++)
          AOb[(size_t)n * HID + dt*32 + l31] = f2bf(oacc[qt][dt][r] * inv);
      }
  }
}

// ---------------------------------------------------------------------------
// out_gemm: [256,512] x AO^T -> out[b][256][2048] fp32 + bias  (R5 version)
// ---------------------------------------------------------------------------
__global__ __launch_bounds__(256, 2) void out_gemm(
    const unsigned short* __restrict__ wo, const unsigned short* __restrict__ AO,
    const float* __restrict__ bias, float* __restrict__ out) {
  __shared__ unsigned short la[64 * 64];
  __shared__ unsigned short lb[128 * 64];
  int o0 = blockIdx.x * 64;
  int n0 = blockIdx.y * 128;
  int b  = blockIdx.z;
  int t  = threadIdx.x;
  int wv = t >> 6, l = t & 63, l15 = l & 15, q = l >> 4;
  int wm = (wv & 1) * 32, wn = (wv >> 1) * 64;
  f32x4 acc[2][4];
#pragma unroll
  for (int i = 0; i < 2; i++)
#pragma unroll
    for (int j = 0; j < 4; j++) acc[i][j] = (f32x4){0.f,0.f,0.f,0.f};
  const unsigned short* Ag = wo + (size_t)o0 * HID;
  const unsigned short* Bg = AO + ((size_t)b * SEQ + n0) * HID;
  int lrow8 = l >> 3, lcol = l & 7;
  for (int kk = 0; kk < 8; kk++) {
    int k0 = kk * 64;
    __syncthreads();
#pragma unroll
    for (int c0 = 0; c0 < 2; c0++) {
      int c = wv * 2 + c0;
      int row = c * 8 + lrow8;
      int sg = lcol ^ (row & 7);
      gld16(Ag + (size_t)row * HID + k0 + sg * 8, la + c * 512);
    }
#pragma unroll
    for (int c0 = 0; c0 < 4; c0++) {
      int c = wv * 4 + c0;
      int row = c * 8 + lrow8;
      int sg = lcol ^ (row & 7);
      gld16(Bg + (size_t)row * HID + k0 + sg * 8, lb + c * 512);
    }
    __syncthreads();
#pragma unroll
    for (int kh = 0; kh < 2; kh++) {
      bf16x8 af[2], bfr[4];
#pragma unroll
      for (int mt = 0; mt < 2; mt++) {
        int row = wm + mt*16 + l15;
        af[mt] = *(const bf16x8*)(la + row*64 + ((kh*4 + q) ^ (row & 7)) * 8);
      }
#pragma unroll
      for (int nt = 0; nt < 4; nt++) {
        int row = wn + nt*16 + l15;
        bfr[nt] = *(const bf16x8*)(lb + row*64 + ((kh*4 + q) ^ (row & 7)) * 8);
      }
#pragma unroll
      for (int mt = 0; mt < 2; mt++)
#pragma unroll
        for (int nt = 0; nt < 4; nt++)
          acc[mt][nt] = __builtin_amdgcn_mfma_f32_16x16x32_bf16(af[mt], bfr[nt], acc[mt][nt], 0,0,0);
    }
  }
#pragma unroll
  for (int mt = 0; mt < 2; mt++)
#pragma unroll
    for (int nt = 0; nt < 4; nt++)
#pragma unroll
      for (int r = 0; r < 4; r++) {
        int o2 = o0 + wm + mt*16 + q*4 + r;
        int n  = n0 + wn + nt*16 + l15;
        out[((size_t)b * DIMC + o2) * SEQ + n] = acc[mt][nt][r] + bias[o2];
      }
}

extern "C" void kernel_launch(void* const* d_in, const int* in_sizes, int n_in,
                              void* d_out, int out_size, void* d_ws, size_t ws_size,
                              hipStream_t stream) {
  const float* x    = (const float*)d_in[0];
  const float* wqkv = (const float*)d_in[1];
  const float* wout = (const float*)d_in[2];
  const float* bout = (const float*)d_in[3];
  float* out = (float*)d_out;
  char* ws = (char*)d_ws;
  unsigned short* wqkv_b = (unsigned short*)(ws);
  unsigned short* wout_b = (unsigned short*)(ws + 786432);
  unsigned short* xT     = (unsigned short*)(ws + 1048576);
  unsigned short* Qs     = (unsigned short*)(ws + 5242880);
  unsigned short* Ks     = (unsigned short*)(ws + 13631488);
  unsigned short* Vt     = (unsigned short*)(ws + 22020096);
  unsigned short* AO     = (unsigned short*)(ws + 30408704);
  prep_kernel<<<1024, 256, 0, stream>>>(x, wqkv, wout, wqkv_b, wout_b, xT);
  qkv_gemm<<<dim3(12, 16, 4), 256, 0, stream>>>(wqkv_b, xT, Qs, Ks, Vt);
  attn_kernel<<<dim3(32, 32), 256, 0, stream>>>(Qs, Ks, Vt, AO);
  out_gemm<<<dim3(4, 16, 4), 256, 0, stream>>>(wout_b, AO, bout, out);
}

// Round 8
// 154.791 us; speedup vs baseline: 3.7840x; 3.7840x over previous
//
#include <hip/hip_runtime.h>
#include <stdint.h>

#define SEQ  2048
#define DIMC 256
#define HID  512
#define NH   8
#define DH   64

typedef __attribute__((ext_vector_type(8))) short bf16x8;
typedef __attribute__((ext_vector_type(4))) float f32x4;
typedef __attribute__((ext_vector_type(16))) float f32x16;
typedef __attribute__((ext_vector_type(2))) unsigned uint2v;
typedef __attribute__((address_space(1))) const uint32_t guint_t;
typedef __attribute__((address_space(3))) uint32_t luint_t;

__device__ __forceinline__ void gld16(const void* g, void* l) {
  __builtin_amdgcn_global_load_lds((guint_t*)g, (luint_t*)l, 16, 0, 0);
}

__device__ __forceinline__ uint32_t fbits(float f) {
  union { float f; uint32_t u; } v; v.f = f; return v.u;
}
__device__ __forceinline__ unsigned short f2bf(float f) {
  uint32_t u = fbits(f);
  return (unsigned short)((u + 0x7FFFu + ((u >> 16) & 1u)) >> 16);
}
// pack two fp32 (raw bits) -> (bf16,bf16) dword, round-half-up
__device__ __forceinline__ uint32_t pku(uint32_t u0, uint32_t u1) {
  return __builtin_amdgcn_perm(u1 + 0x8000u, u0 + 0x8000u, 0x07060302u);
}

// exchange hi 32 lanes of a with lo 32 lanes of b
__device__ __forceinline__ void swap32(uint32_t& a, uint32_t& b) {
#if __has_builtin(__builtin_amdgcn_permlane32_swap)
  uint2v r = __builtin_amdgcn_permlane32_swap(a, b, false, false);
  a = r[0]; b = r[1];
#else
  uint32_t aw = __shfl_xor(a, 32);
  uint32_t bw = __shfl_xor(b, 32);
  bool lo = (threadIdx.x & 32) == 0;
  uint32_t an = lo ? a : bw;
  uint32_t bn = lo ? aw : b;
  a = an; b = bn;
#endif
}

// ---------------------------------------------------------------------------
// prep: w_qkv -> bf16 (Q rows pre-scaled by SCALE*log2e), w_out -> bf16,
//       x [b][i][n] fp32 -> xT [b][n][i] bf16
// ---------------------------------------------------------------------------
__global__ __launch_bounds__(256) void prep_kernel(
    const float* __restrict__ x, const float* __restrict__ wqkv,
    const float* __restrict__ wout,
    unsigned short* __restrict__ wqkv_b, unsigned short* __restrict__ wout_b,
    unsigned short* __restrict__ xT) {
  __shared__ float tile[64][65];
  int blk = blockIdx.x;
  int t = threadIdx.x;
  if (blk < 384) {
    int idx = blk * 1024 + t * 4;
    float4 v = *(const float4*)(wqkv + idx);
    float s = ((idx >> 8) < HID) ? 0.18033688011112042f : 1.0f;  // 0.125*log2(e)
    ushort4 o;
    o.x = f2bf(v.x * s); o.y = f2bf(v.y * s);
    o.z = f2bf(v.z * s); o.w = f2bf(v.w * s);
    *(ushort4*)(wqkv_b + idx) = o;
    return;
  }
  if (blk < 512) {
    int idx = (blk - 384) * 1024 + t * 4;
    float4 v = *(const float4*)(wout + idx);
    ushort4 o;
    o.x = f2bf(v.x); o.y = f2bf(v.y); o.z = f2bf(v.z); o.w = f2bf(v.w);
    *(ushort4*)(wout_b + idx) = o;
    return;
  }
  int tid = blk - 512;
  int b  = tid >> 7;
  int r  = tid & 127;
  int i0 = (r >> 5) * 64;
  int n0 = (r & 31) * 64;
  const float* xb = x + (size_t)b * DIMC * SEQ;
  int tn = t & 15, ti = t >> 4;
#pragma unroll
  for (int j = 0; j < 4; j++) {
    int il = ti + j * 16;
    float4 v = *(const float4*)(xb + (size_t)(i0 + il) * SEQ + n0 + tn * 4);
    tile[il][tn*4+0] = v.x; tile[il][tn*4+1] = v.y;
    tile[il][tn*4+2] = v.z; tile[il][tn*4+3] = v.w;
  }
  __syncthreads();
  unsigned short* xTb = xT + (size_t)b * SEQ * DIMC;
#pragma unroll
  for (int j = 0; j < 4; j++) {
    int nl = ti + j * 16;
    int i4 = tn * 4;
    uint2 pk;
    pk.x = (uint32_t)f2bf(tile[i4+0][nl]) | ((uint32_t)f2bf(tile[i4+1][nl]) << 16);
    pk.y = (uint32_t)f2bf(tile[i4+2][nl]) | ((uint32_t)f2bf(tile[i4+3][nl]) << 16);
    *(uint2*)(xTb + (size_t)(n0 + nl) * DIMC + i0 + i4) = pk;
  }
}

// ---------------------------------------------------------------------------
// qkv_gemm: 128x128 tile, BK=64, gld16 swizzled staging
// ---------------------------------------------------------------------------
__global__ __launch_bounds__(256, 2) void qkv_gemm(
    const unsigned short* __restrict__ wq, const unsigned short* __restrict__ xT,
    unsigned short* __restrict__ Qs, unsigned short* __restrict__ Ks,
    unsigned short* __restrict__ Vt) {
  __shared__ unsigned short lds[17408];
  unsigned short* la = lds;
  unsigned short* lb = lds + 8192;
  int o0 = blockIdx.x * 128;
  int n0 = blockIdx.y * 128;
  int b  = blockIdx.z;
  int t  = threadIdx.x;
  int wv = t >> 6, l = t & 63, l15 = l & 15, q = l >> 4;
  int wm = (wv & 1) * 64, wn = (wv >> 1) * 64;
  f32x4 acc[4][4];
#pragma unroll
  for (int i = 0; i < 4; i++)
#pragma unroll
    for (int j = 0; j < 4; j++) acc[i][j] = (f32x4){0.f, 0.f, 0.f, 0.f};
  const unsigned short* Ag = wq + (size_t)o0 * DIMC;
  const unsigned short* Bg = xT + ((size_t)b * SEQ + n0) * DIMC;
  int lrow8 = l >> 3, lcol = l & 7;
  for (int kk = 0; kk < 4; kk++) {
    int k0 = kk * 64;
    __syncthreads();
#pragma unroll
    for (int c0 = 0; c0 < 4; c0++) {
      int c = wv * 4 + c0;
      int row = c * 8 + lrow8;
      int sg = lcol ^ (row & 7);
      gld16(Ag + (size_t)row * DIMC + k0 + sg * 8, la + c * 512);
      gld16(Bg + (size_t)row * DIMC + k0 + sg * 8, lb + c * 512);
    }
    __syncthreads();
#pragma unroll
    for (int kh = 0; kh < 2; kh++) {
      bf16x8 af[4], bfr[4];
#pragma unroll
      for (int mt = 0; mt < 4; mt++) {
        int row = wm + mt*16 + l15;
        af[mt] = *(const bf16x8*)(la + row*64 + ((kh*4 + q) ^ (row & 7)) * 8);
      }
#pragma unroll
      for (int nt = 0; nt < 4; nt++) {
        int row = wn + nt*16 + l15;
        bfr[nt] = *(const bf16x8*)(lb + row*64 + ((kh*4 + q) ^ (row & 7)) * 8);
      }
#pragma unroll
      for (int mt = 0; mt < 4; mt++)
#pragma unroll
        for (int nt = 0; nt < 4; nt++)
          acc[mt][nt] = __builtin_amdgcn_mfma_f32_16x16x32_bf16(af[mt], bfr[nt], acc[mt][nt], 0, 0, 0);
    }
  }
  __syncthreads();
  int seg3 = o0 >> 9;
  int h0   = (o0 & 511) >> 6;
  if (seg3 == 2) {
#pragma unroll
    for (int mt = 0; mt < 4; mt++)
#pragma unroll
      for (int nt = 0; nt < 4; nt++)
#pragma unroll
        for (int r = 0; r < 4; r++) {
          int ol = wm + mt * 16 + q * 4 + r;
          int h = h0 + (ol >> 6), d = ol & 63;
          int n = n0 + wn + nt * 16 + l15;
          Vt[(((size_t)b * NH + h) * DH + d) * SEQ + n] = f2bf(acc[mt][nt][r]);
        }
  } else {
    unsigned short* dst = (seg3 == 0) ? Qs : Ks;
#pragma unroll
    for (int mt = 0; mt < 4; mt++)
#pragma unroll
      for (int nt = 0; nt < 4; nt++)
#pragma unroll
        for (int r = 0; r < 4; r++) {
          int ol = wm + mt * 16 + q * 4 + r;
          int nn = wn + nt * 16 + l15;
          lds[nn * 136 + ol] = f2bf(acc[mt][nt][r]);
        }
    __syncthreads();
#pragma unroll
    for (int i = 0; i < 8; i++) {
      int idx = i * 256 + t;
      int nn  = idx >> 4;
      int olb = (idx & 15) * 8;
      uint4 v = *(const uint4*)(lds + nn * 136 + olb);
      int h = h0 + (olb >> 6), d = olb & 63;
      *(uint4*)(dst + (((size_t)b * NH + h) * SEQ + n0 + nn) * DH + d) = v;
    }
  }
}

// ---------------------------------------------------------------------------
// attn: TLP-first. Grid 1024 blocks x 256 thr (4 waves) -> 4 blocks/CU
// (LDS 33 KB, VGPR ~112 natural). Block = 64 queries; wave cg owns keys
// [cg*512, cg*512+512). K/V frags straight from global (L2-hot) --
// zero LDS, zero barriers in the K-loop. Register P-transform.
// Additive partials -> LDS tree-combine + normalize.
// launch_bounds(256,2): NEVER >2 (R4/R7: arg>=4 forces 64 VGPR -> spills).
// ---------------------------------------------------------------------------
__global__ __launch_bounds__(256, 2) void attn_kernel(
    const unsigned short* __restrict__ Qs, const unsigned short* __restrict__ Ks,
    const unsigned short* __restrict__ Vt, unsigned short* __restrict__ AO) {
  __shared__ float Ocf[8192];     // two 16 KB combine buffers
  __shared__ float Lc[256];       // [cg][64 q] row sums
  int n0 = blockIdx.x * 64;
  int bh = blockIdx.y;
  int b = bh >> 3, h = bh & 7;
  int t = threadIdx.x;
  int cg = t >> 6, l = t & 63, l31 = l & 31, lh = l >> 5;
  // Q B-frags, once
  const unsigned short* Qg = Qs + ((size_t)bh * SEQ + n0) * DH;
  bf16x8 qb[2][4];
#pragma unroll
  for (int qt = 0; qt < 2; qt++)
#pragma unroll
    for (int kc = 0; kc < 4; kc++)
      qb[qt][kc] = *(const bf16x8*)(Qg + (qt*32 + l31) * DH + kc*16 + lh*8);
  f32x16 oacc[2][2];
  float lrowp[2] = {0.f, 0.f};
#pragma unroll
  for (int qt = 0; qt < 2; qt++)
#pragma unroll
    for (int dt = 0; dt < 2; dt++)
#pragma unroll
      for (int r = 0; r < 16; r++) oacc[qt][dt][r] = 0.f;
  const unsigned short* Kg = Ks + ((size_t)bh * SEQ + cg * 512) * DH;
  const unsigned short* Vg = Vt + (size_t)bh * DH * SEQ + cg * 512;
  for (int it = 0; it < 16; it++) {
    int kb = it * 32;
    // V B-frags early (independent; hide latency under QK+exp)
    bf16x8 vf[2][2];
#pragma unroll
    for (int kc2 = 0; kc2 < 2; kc2++)
#pragma unroll
      for (int dt = 0; dt < 2; dt++)
        vf[kc2][dt] = *(const bf16x8*)(Vg + (size_t)(dt*32 + l31) * SEQ + kb + kc2*16 + lh*8);
    // S^T = K Q^T : D[m=key][n=query=l31]
    f32x16 st[2];
#pragma unroll
    for (int qt = 0; qt < 2; qt++)
#pragma unroll
      for (int r = 0; r < 16; r++) st[qt][r] = 0.f;
#pragma unroll
    for (int kc = 0; kc < 4; kc++) {
      bf16x8 kf = *(const bf16x8*)(Kg + (size_t)(kb + l31) * DH + kc*16 + lh*8);
      st[0] = __builtin_amdgcn_mfma_f32_32x32x16_bf16(kf, qb[0][kc], st[0], 0, 0, 0);
      st[1] = __builtin_amdgcn_mfma_f32_32x32x16_bf16(kf, qb[1][kc], st[1], 0, 0, 0);
    }
#pragma unroll
    for (int qt = 0; qt < 2; qt++) {
      float p[16];
      float s0 = 0.f;
#pragma unroll
      for (int r = 0; r < 16; r++) { p[r] = __builtin_amdgcn_exp2f(st[qt][r]); s0 += p[r]; }
      lrowp[qt] += s0;
      bf16x8 af[2];
#pragma unroll
      for (int hf = 0; hf < 2; hf++) {
        uint32_t xs[4], ys[4];
#pragma unroll
        for (int j = 0; j < 4; j++) {
          xs[j] = fbits(p[hf*8 + j]);
          ys[j] = fbits(p[hf*8 + 4 + j]);
          swap32(xs[j], ys[j]);
        }
        union { uint32_t u[4]; bf16x8 v; } cv;
        cv.u[0] = pku(xs[0], xs[1]);
        cv.u[1] = pku(xs[2], xs[3]);
        cv.u[2] = pku(ys[0], ys[1]);
        cv.u[3] = pku(ys[2], ys[3]);
        af[hf] = cv.v;
      }
#pragma unroll
      for (int kc2 = 0; kc2 < 2; kc2++)
#pragma unroll
        for (int dt = 0; dt < 2; dt++)
          oacc[qt][dt] = __builtin_amdgcn_mfma_f32_32x32x16_bf16(af[kc2], vf[kc2][dt], oacc[qt][dt], 0, 0, 0);
    }
  }
  // ---- row sums ----
#pragma unroll
  for (int qt = 0; qt < 2; qt++) {
    float v = lrowp[qt];
    v += __shfl_xor(v, 32);
    if (l < 32) Lc[cg * 64 + qt * 32 + l31] = v;
  }
  // ---- 4-partial additive tree combine in LDS ----
  auto dump = [&](float* R) {
#pragma unroll
    for (int qt = 0; qt < 2; qt++)
#pragma unroll
      for (int dt = 0; dt < 2; dt++)
#pragma unroll
        for (int rr = 0; rr < 4; rr++)
          *(f32x4*)(R + ((qt*2+dt)*4 + rr) * 256 + l * 4) =
            (f32x4){oacc[qt][dt][rr*4+0], oacc[qt][dt][rr*4+1],
                    oacc[qt][dt][rr*4+2], oacc[qt][dt][rr*4+3]};
  };
  auto addin = [&](const float* R) {
#pragma unroll
    for (int qt = 0; qt < 2; qt++)
#pragma unroll
      for (int dt = 0; dt < 2; dt++)
#pragma unroll
        for (int rr = 0; rr < 4; rr++) {
          f32x4 v = *(const f32x4*)(R + ((qt*2+dt)*4 + rr) * 256 + l * 4);
          oacc[qt][dt][rr*4+0] += v[0]; oacc[qt][dt][rr*4+1] += v[1];
          oacc[qt][dt][rr*4+2] += v[2]; oacc[qt][dt][rr*4+3] += v[3];
        }
  };
  if (cg == 1) dump(Ocf);
  if (cg == 3) dump(Ocf + 4096);
  __syncthreads();
  if (cg == 0) addin(Ocf);
  if (cg == 2) addin(Ocf + 4096);
  __syncthreads();
  if (cg == 2) dump(Ocf);
  __syncthreads();
  if (cg == 0) {
    addin(Ocf);
    unsigned short* AOb = AO + (size_t)b * SEQ * HID + h * DH;
#pragma unroll
    for (int qt = 0; qt < 2; qt++)
#pragma unroll
      for (int r = 0; r < 16; r++) {
        int qrow = qt*32 + (r & 3) + 8*(r >> 2) + 4*lh;
        float lsum = Lc[qrow] + Lc[64 + qrow] + Lc[128 + qrow] + Lc[192 + qrow];
        float inv = __builtin_amdgcn_rcpf(lsum);
        int n = n0 + qrow;
#pragma unroll
        for (int dt = 0; dt < 2; dt++)
          AOb[(size_t)n * HID + dt*32 + l31] = f2bf(oacc[qt][dt][r] * inv);
      }
  }
}

// ---------------------------------------------------------------------------
// out_gemm: [256,512] x AO^T -> out[b][256][2048] fp32 + bias
// ---------------------------------------------------------------------------
__global__ __launch_bounds__(256, 2) void out_gemm(
    const unsigned short* __restrict__ wo, const unsigned short* __restrict__ AO,
    const float* __restrict__ bias, float* __restrict__ out) {
  __shared__ unsigned short la[64 * 64];
  __shared__ unsigned short lb[128 * 64];
  int o0 = blockIdx.x * 64;
  int n0 = blockIdx.y * 128;
  int b  = blockIdx.z;
  int t  = threadIdx.x;
  int wv = t >> 6, l = t & 63, l15 = l & 15, q = l >> 4;
  int wm = (wv & 1) * 32, wn = (wv >> 1) * 64;
  f32x4 acc[2][4];
#pragma unroll
  for (int i = 0; i < 2; i++)
#pragma unroll
    for (int j = 0; j < 4; j++) acc[i][j] = (f32x4){0.f,0.f,0.f,0.f};
  const unsigned short* Ag = wo + (size_t)o0 * HID;
  const unsigned short* Bg = AO + ((size_t)b * SEQ + n0) * HID;
  int lrow8 = l >> 3, lcol = l & 7;
  for (int kk = 0; kk < 8; kk++) {
    int k0 = kk * 64;
    __syncthreads();
#pragma unroll
    for (int c0 = 0; c0 < 2; c0++) {
      int c = wv * 2 + c0;
      int row = c * 8 + lrow8;
      int sg = lcol ^ (row & 7);
      gld16(Ag + (size_t)row * HID + k0 + sg * 8, la + c * 512);
    }
#pragma unroll
    for (int c0 = 0; c0 < 4; c0++) {
      int c = wv * 4 + c0;
      int row = c * 8 + lrow8;
      int sg = lcol ^ (row & 7);
      gld16(Bg + (size_t)row * HID + k0 + sg * 8, lb + c * 512);
    }
    __syncthreads();
#pragma unroll
    for (int kh = 0; kh < 2; kh++) {
      bf16x8 af[2], bfr[4];
#pragma unroll
      for (int mt = 0; mt < 2; mt++) {
        int row = wm + mt*16 + l15;
        af[mt] = *(const bf16x8*)(la + row*64 + ((kh*4 + q) ^ (row & 7)) * 8);
      }
#pragma unroll
      for (int nt = 0; nt < 4; nt++) {
        int row = wn + nt*16 + l15;
        bfr[nt] = *(const bf16x8*)(lb + row*64 + ((kh*4 + q) ^ (row & 7)) * 8);
      }
#pragma unroll
      for (int mt = 0; mt < 2; mt++)
#pragma unroll
        for (int nt = 0; nt < 4; nt++)
          acc[mt][nt] = __builtin_amdgcn_mfma_f32_16x16x32_bf16(af[mt], bfr[nt], acc[mt][nt], 0,0,0);
    }
  }
#pragma unroll
  for (int mt = 0; mt < 2; mt++)
#pragma unroll
    for (int nt = 0; nt < 4; nt++)
#pragma unroll
      for (int r = 0; r < 4; r++) {
        int o2 = o0 + wm + mt*16 + q*4 + r;
        int n  = n0 + wn + nt*16 + l15;
        out[((size_t)b * DIMC + o2) * SEQ + n] = acc[mt][nt][r] + bias[o2];
      }
}

extern "C" void kernel_launch(void* const* d_in, const int* in_sizes, int n_in,
                              void* d_out, int out_size, void* d_ws, size_t ws_size,
                              hipStream_t stream) {
  const float* x    = (const float*)d_in[0];
  const float* wqkv = (const float*)d_in[1];
  const float* wout = (const float*)d_in[2];
  const float* bout = (const float*)d_in[3];
  float* out = (float*)d_out;
  char* ws = (char*)d_ws;
  unsigned short* wqkv_b = (unsigned short*)(ws);
  unsigned short* wout_b = (unsigned short*)(ws + 786432);
  unsigned short* xT     = (unsigned short*)(ws + 1048576);
  unsigned short* Qs     = (unsigned short*)(ws + 5242880);
  unsigned short* Ks     = (unsigned short*)(ws + 13631488);
  unsigned short* Vt     = (unsigned short*)(ws + 22020096);
  unsigned short* AO     = (unsigned short*)(ws + 30408704);
  prep_kernel<<<1024, 256, 0, stream>>>(x, wqkv, wout, wqkv_b, wout_b, xT);
  qkv_gemm<<<dim3(12, 16, 4), 256, 0, stream>>>(wqkv_b, xT, Qs, Ks, Vt);
  attn_kernel<<<dim3(32, 32), 256, 0, stream>>>(Qs, Ks, Vt, AO);
  out_gemm<<<dim3(4, 16, 4), 256, 0, stream>>>(wout_b, AO, bout, out);
}

// Round 9
// 145.433 us; speedup vs baseline: 4.0275x; 1.0643x over previous
//
#include <hip/hip_runtime.h>
#include <stdint.h>

#define SEQ  2048
#define DIMC 256
#define HID  512
#define NH   8
#define DH   64

typedef __attribute__((ext_vector_type(8))) short bf16x8;
typedef __attribute__((ext_vector_type(4))) float f32x4;
typedef __attribute__((ext_vector_type(16))) float f32x16;
typedef __attribute__((ext_vector_type(2))) unsigned uint2v;
typedef __attribute__((address_space(1))) const uint32_t guint_t;
typedef __attribute__((address_space(3))) uint32_t luint_t;

__device__ __forceinline__ void gld16(const void* g, void* l) {
  __builtin_amdgcn_global_load_lds((guint_t*)g, (luint_t*)l, 16, 0, 0);
}

__device__ __forceinline__ uint32_t fbits(float f) {
  union { float f; uint32_t u; } v; v.f = f; return v.u;
}
__device__ __forceinline__ unsigned short f2bf(float f) {
  uint32_t u = fbits(f);
  return (unsigned short)((u + 0x7FFFu + ((u >> 16) & 1u)) >> 16);
}
// pack two fp32 (raw bits) -> (bf16,bf16) dword, round-half-up
__device__ __forceinline__ uint32_t pku(uint32_t u0, uint32_t u1) {
  return __builtin_amdgcn_perm(u1 + 0x8000u, u0 + 0x8000u, 0x07060302u);
}

// exchange hi 32 lanes of a with lo 32 lanes of b
__device__ __forceinline__ void swap32(uint32_t& a, uint32_t& b) {
#if __has_builtin(__builtin_amdgcn_permlane32_swap)
  uint2v r = __builtin_amdgcn_permlane32_swap(a, b, false, false);
  a = r[0]; b = r[1];
#else
  uint32_t aw = __shfl_xor(a, 32);
  uint32_t bw = __shfl_xor(b, 32);
  bool lo = (threadIdx.x & 32) == 0;
  uint32_t an = lo ? a : bw;
  uint32_t bn = lo ? aw : b;
  a = an; b = bn;
#endif
}

// ---------------------------------------------------------------------------
// prep: w_qkv -> bf16 (Q rows pre-scaled by SCALE*log2e), w_out -> bf16,
//       x [b][i][n] fp32 -> xT [b][n][i] bf16
// ---------------------------------------------------------------------------
__global__ __launch_bounds__(256) void prep_kernel(
    const float* __restrict__ x, const float* __restrict__ wqkv,
    const float* __restrict__ wout,
    unsigned short* __restrict__ wqkv_b, unsigned short* __restrict__ wout_b,
    unsigned short* __restrict__ xT) {
  __shared__ float tile[64][65];
  int blk = blockIdx.x;
  int t = threadIdx.x;
  if (blk < 384) {
    int idx = blk * 1024 + t * 4;
    float4 v = *(const float4*)(wqkv + idx);
    float s = ((idx >> 8) < HID) ? 0.18033688011112042f : 1.0f;  // 0.125*log2(e)
    ushort4 o;
    o.x = f2bf(v.x * s); o.y = f2bf(v.y * s);
    o.z = f2bf(v.z * s); o.w = f2bf(v.w * s);
    *(ushort4*)(wqkv_b + idx) = o;
    return;
  }
  if (blk < 512) {
    int idx = (blk - 384) * 1024 + t * 4;
    float4 v = *(const float4*)(wout + idx);
    ushort4 o;
    o.x = f2bf(v.x); o.y = f2bf(v.y); o.z = f2bf(v.z); o.w = f2bf(v.w);
    *(ushort4*)(wout_b + idx) = o;
    return;
  }
  int tid = blk - 512;
  int b  = tid >> 7;
  int r  = tid & 127;
  int i0 = (r >> 5) * 64;
  int n0 = (r & 31) * 64;
  const float* xb = x + (size_t)b * DIMC * SEQ;
  int tn = t & 15, ti = t >> 4;
#pragma unroll
  for (int j = 0; j < 4; j++) {
    int il = ti + j * 16;
    float4 v = *(const float4*)(xb + (size_t)(i0 + il) * SEQ + n0 + tn * 4);
    tile[il][tn*4+0] = v.x; tile[il][tn*4+1] = v.y;
    tile[il][tn*4+2] = v.z; tile[il][tn*4+3] = v.w;
  }
  __syncthreads();
  unsigned short* xTb = xT + (size_t)b * SEQ * DIMC;
#pragma unroll
  for (int j = 0; j < 4; j++) {
    int nl = ti + j * 16;
    int i4 = tn * 4;
    uint2 pk;
    pk.x = (uint32_t)f2bf(tile[i4+0][nl]) | ((uint32_t)f2bf(tile[i4+1][nl]) << 16);
    pk.y = (uint32_t)f2bf(tile[i4+2][nl]) | ((uint32_t)f2bf(tile[i4+3][nl]) << 16);
    *(uint2*)(xTb + (size_t)(n0 + nl) * DIMC + i0 + i4) = pk;
  }
}

// ---------------------------------------------------------------------------
// qkv_gemm: 128x128 tile, BK=64, gld16 swizzled staging
// ---------------------------------------------------------------------------
__global__ __launch_bounds__(256, 2) void qkv_gemm(
    const unsigned short* __restrict__ wq, const unsigned short* __restrict__ xT,
    unsigned short* __restrict__ Qs, unsigned short* __restrict__ Ks,
    unsigned short* __restrict__ Vt) {
  __shared__ unsigned short lds[17408];
  unsigned short* la = lds;
  unsigned short* lb = lds + 8192;
  int o0 = blockIdx.x * 128;
  int n0 = blockIdx.y * 128;
  int b  = blockIdx.z;
  int t  = threadIdx.x;
  int wv = t >> 6, l = t & 63, l15 = l & 15, q = l >> 4;
  int wm = (wv & 1) * 64, wn = (wv >> 1) * 64;
  f32x4 acc[4][4];
#pragma unroll
  for (int i = 0; i < 4; i++)
#pragma unroll
    for (int j = 0; j < 4; j++) acc[i][j] = (f32x4){0.f, 0.f, 0.f, 0.f};
  const unsigned short* Ag = wq + (size_t)o0 * DIMC;
  const unsigned short* Bg = xT + ((size_t)b * SEQ + n0) * DIMC;
  int lrow8 = l >> 3, lcol = l & 7;
  for (int kk = 0; kk < 4; kk++) {
    int k0 = kk * 64;
    __syncthreads();
#pragma unroll
    for (int c0 = 0; c0 < 4; c0++) {
      int c = wv * 4 + c0;
      int row = c * 8 + lrow8;
      int sg = lcol ^ (row & 7);
      gld16(Ag + (size_t)row * DIMC + k0 + sg * 8, la + c * 512);
      gld16(Bg + (size_t)row * DIMC + k0 + sg * 8, lb + c * 512);
    }
    __syncthreads();
#pragma unroll
    for (int kh = 0; kh < 2; kh++) {
      bf16x8 af[4], bfr[4];
#pragma unroll
      for (int mt = 0; mt < 4; mt++) {
        int row = wm + mt*16 + l15;
        af[mt] = *(const bf16x8*)(la + row*64 + ((kh*4 + q) ^ (row & 7)) * 8);
      }
#pragma unroll
      for (int nt = 0; nt < 4; nt++) {
        int row = wn + nt*16 + l15;
        bfr[nt] = *(const bf16x8*)(lb + row*64 + ((kh*4 + q) ^ (row & 7)) * 8);
      }
#pragma unroll
      for (int mt = 0; mt < 4; mt++)
#pragma unroll
        for (int nt = 0; nt < 4; nt++)
          acc[mt][nt] = __builtin_amdgcn_mfma_f32_16x16x32_bf16(af[mt], bfr[nt], acc[mt][nt], 0, 0, 0);
    }
  }
  __syncthreads();
  int seg3 = o0 >> 9;
  int h0   = (o0 & 511) >> 6;
  if (seg3 == 2) {
#pragma unroll
    for (int mt = 0; mt < 4; mt++)
#pragma unroll
      for (int nt = 0; nt < 4; nt++)
#pragma unroll
        for (int r = 0; r < 4; r++) {
          int ol = wm + mt * 16 + q * 4 + r;
          int h = h0 + (ol >> 6), d = ol & 63;
          int n = n0 + wn + nt * 16 + l15;
          Vt[(((size_t)b * NH + h) * DH + d) * SEQ + n] = f2bf(acc[mt][nt][r]);
        }
  } else {
    unsigned short* dst = (seg3 == 0) ? Qs : Ks;
#pragma unroll
    for (int mt = 0; mt < 4; mt++)
#pragma unroll
      for (int nt = 0; nt < 4; nt++)
#pragma unroll
        for (int r = 0; r < 4; r++) {
          int ol = wm + mt * 16 + q * 4 + r;
          int nn = wn + nt * 16 + l15;
          lds[nn * 136 + ol] = f2bf(acc[mt][nt][r]);
        }
    __syncthreads();
#pragma unroll
    for (int i = 0; i < 8; i++) {
      int idx = i * 256 + t;
      int nn  = idx >> 4;
      int olb = (idx & 15) * 8;
      uint4 v = *(const uint4*)(lds + nn * 136 + olb);
      int h = h0 + (olb >> 6), d = olb & 63;
      *(uint4*)(dst + (((size_t)b * NH + h) * SEQ + n0 + nn) * DH + d) = v;
    }
  }
}

// ---------------------------------------------------------------------------
// attn: 1024 blocks x 256 thr (4 waves) -> 4 blocks/CU. Block = 64 queries;
// wave cg owns keys [cg*512, cg*512+512) in 16 tiles of 32 keys.
// Each wave stages its OWN private 8KB K+V LDS tile via gld16 + explicit
// vmcnt(0) -- NO barriers in the K-loop; waves fully independent.
// Frag reads from LDS (~120cyc) not L2 (~300-900). Register P-transform.
// Additive partials -> barrier + LDS tree-combine (reuses staging region).
// launch_bounds 2nd arg NEVER >2 (R4/R7: >=4 forces 64 VGPR -> spills).
// ---------------------------------------------------------------------------
__global__ __launch_bounds__(256, 2) void attn_kernel(
    const unsigned short* __restrict__ Qs, const unsigned short* __restrict__ Ks,
    const unsigned short* __restrict__ Vt, unsigned short* __restrict__ AO) {
  __shared__ unsigned short KV[16384];  // 4 waves x (K 2048 + V 2048 shorts)
  __shared__ float Lc[256];             // [cg][64 q] row sums
  int n0 = blockIdx.x * 64;
  int bh = blockIdx.y;
  int b = bh >> 3, h = bh & 7;
  int t = threadIdx.x;
  int cg = t >> 6, l = t & 63, l31 = l & 31, lh = l >> 5;
  // Q B-frags, once
  const unsigned short* Qg = Qs + ((size_t)bh * SEQ + n0) * DH;
  bf16x8 qb[2][4];
#pragma unroll
  for (int qt = 0; qt < 2; qt++)
#pragma unroll
    for (int kc = 0; kc < 4; kc++)
      qb[qt][kc] = *(const bf16x8*)(Qg + (qt*32 + l31) * DH + kc*16 + lh*8);
  f32x16 oacc[2][2];
  float lrowp[2] = {0.f, 0.f};
#pragma unroll
  for (int qt = 0; qt < 2; qt++)
#pragma unroll
    for (int dt = 0; dt < 2; dt++)
#pragma unroll
      for (int r = 0; r < 16; r++) oacc[qt][dt][r] = 0.f;
  const unsigned short* Kg = Ks + ((size_t)bh * SEQ + cg * 512) * DH;
  const unsigned short* Vg = Vt + (size_t)bh * DH * SEQ + cg * 512;
  unsigned short* Kw = KV + cg * 4096;     // this wave's private staging
  unsigned short* Vw = Kw + 2048;
  for (int it = 0; it < 16; it++) {
    int kb = it * 32;
    // ---- stage this wave's 32-key K+V tile (8 gld16, swizzled) ----
#pragma unroll
    for (int g = 0; g < 4; g++) {
      int kr = g * 8 + (l >> 3);
      gld16(Kg + (size_t)(kb + kr) * DH + ((l & 7) ^ (kr & 7)) * 8, Kw + g * 512);
    }
#pragma unroll
    for (int g = 0; g < 4; g++) {
      int dr = g * 16 + (l >> 2);
      int seg = (l & 3) ^ ((dr ^ (dr >> 2)) & 3);
      gld16(Vg + (size_t)dr * SEQ + kb + seg * 8, Vw + g * 512);
    }
    __builtin_amdgcn_s_waitcnt(0x0F70);   // vmcnt(0): this wave's tile ready
    // ---- S^T = K Q^T : D[m=key][n=query=l31] ----
    f32x16 st[2];
#pragma unroll
    for (int qt = 0; qt < 2; qt++)
#pragma unroll
      for (int r = 0; r < 16; r++) st[qt][r] = 0.f;
#pragma unroll
    for (int kc = 0; kc < 4; kc++) {
      bf16x8 kf = *(const bf16x8*)(Kw + l31 * 64 + (((kc*2 + lh) ^ (l31 & 7))) * 8);
      st[0] = __builtin_amdgcn_mfma_f32_32x32x16_bf16(kf, qb[0][kc], st[0], 0, 0, 0);
      st[1] = __builtin_amdgcn_mfma_f32_32x32x16_bf16(kf, qb[1][kc], st[1], 0, 0, 0);
    }
    // V B-frags from this wave's LDS
    bf16x8 vf[2][2];
#pragma unroll
    for (int kc2 = 0; kc2 < 2; kc2++)
#pragma unroll
      for (int dt = 0; dt < 2; dt++) {
        int d = dt*32 + l31;
        int hv = (d ^ (d >> 2)) & 3;
        vf[kc2][dt] = *(const bf16x8*)(Vw + d * 32 + (((kc2*2 + lh) ^ hv)) * 8);
      }
#pragma unroll
    for (int qt = 0; qt < 2; qt++) {
      float p[16];
      float s0 = 0.f;
#pragma unroll
      for (int r = 0; r < 16; r++) { p[r] = __builtin_amdgcn_exp2f(st[qt][r]); s0 += p[r]; }
      lrowp[qt] += s0;
      bf16x8 af[2];
#pragma unroll
      for (int hf = 0; hf < 2; hf++) {
        uint32_t xs[4], ys[4];
#pragma unroll
        for (int j = 0; j < 4; j++) {
          xs[j] = fbits(p[hf*8 + j]);
          ys[j] = fbits(p[hf*8 + 4 + j]);
          swap32(xs[j], ys[j]);
        }
        union { uint32_t u[4]; bf16x8 v; } cv;
        cv.u[0] = pku(xs[0], xs[1]);
        cv.u[1] = pku(xs[2], xs[3]);
        cv.u[2] = pku(ys[0], ys[1]);
        cv.u[3] = pku(ys[2], ys[3]);
        af[hf] = cv.v;
      }
#pragma unroll
      for (int kc2 = 0; kc2 < 2; kc2++)
#pragma unroll
        for (int dt = 0; dt < 2; dt++)
          oacc[qt][dt] = __builtin_amdgcn_mfma_f32_32x32x16_bf16(af[kc2], vf[kc2][dt], oacc[qt][dt], 0, 0, 0);
    }
  }
  // ---- row sums ----
#pragma unroll
  for (int qt = 0; qt < 2; qt++) {
    float v = lrowp[qt];
    v += __shfl_xor(v, 32);
    if (l < 32) Lc[cg * 64 + qt * 32 + l31] = v;
  }
  __syncthreads();                 // staging region now free -> reuse as Ocf
  float* Ocf = (float*)KV;         // 8192 floats = 32 KB
  auto dump = [&](float* R) {
#pragma unroll
    for (int qt = 0; qt < 2; qt++)
#pragma unroll
      for (int dt = 0; dt < 2; dt++)
#pragma unroll
        for (int rr = 0; rr < 4; rr++)
          *(f32x4*)(R + ((qt*2+dt)*4 + rr) * 256 + l * 4) =
            (f32x4){oacc[qt][dt][rr*4+0], oacc[qt][dt][rr*4+1],
                    oacc[qt][dt][rr*4+2], oacc[qt][dt][rr*4+3]};
  };
  auto addin = [&](const float* R) {
#pragma unroll
    for (int qt = 0; qt < 2; qt++)
#pragma unroll
      for (int dt = 0; dt < 2; dt++)
#pragma unroll
        for (int rr = 0; rr < 4; rr++) {
          f32x4 v = *(const f32x4*)(R + ((qt*2+dt)*4 + rr) * 256 + l * 4);
          oacc[qt][dt][rr*4+0] += v[0]; oacc[qt][dt][rr*4+1] += v[1];
          oacc[qt][dt][rr*4+2] += v[2]; oacc[qt][dt][rr*4+3] += v[3];
        }
  };
  if (cg == 1) dump(Ocf);
  if (cg == 3) dump(Ocf + 4096);
  __syncthreads();
  if (cg == 0) addin(Ocf);
  if (cg == 2) addin(Ocf + 4096);
  __syncthreads();
  if (cg == 2) dump(Ocf);
  __syncthreads();
  if (cg == 0) {
    addin(Ocf);
    unsigned short* AOb = AO + (size_t)b * SEQ * HID + h * DH;
#pragma unroll
    for (int qt = 0; qt < 2; qt++)
#pragma unroll
      for (int r = 0; r < 16; r++) {
        int qrow = qt*32 + (r & 3) + 8*(r >> 2) + 4*lh;
        float lsum = Lc[qrow] + Lc[64 + qrow] + Lc[128 + qrow] + Lc[192 + qrow];
        float inv = __builtin_amdgcn_rcpf(lsum);
        int n = n0 + qrow;
#pragma unroll
        for (int dt = 0; dt < 2; dt++)
          AOb[(size_t)n * HID + dt*32 + l31] = f2bf(oacc[qt][dt][r] * inv);
      }
  }
}

// ---------------------------------------------------------------------------
// out_gemm: [256,512] x AO^T -> out[b][256][2048] fp32 + bias.
// 32x128 tile, grid (8,16,4)=512 -> 2 blocks/CU.
// ---------------------------------------------------------------------------
__global__ __launch_bounds__(256, 2) void out_gemm(
    const unsigned short* __restrict__ wo, const unsigned short* __restrict__ AO,
    const float* __restrict__ bias, float* __restrict__ out) {
  __shared__ unsigned short la[32 * 64];
  __shared__ unsigned short lb[128 * 64];
  int o0 = blockIdx.x * 32;
  int n0 = blockIdx.y * 128;
  int b  = blockIdx.z;
  int t  = threadIdx.x;
  int wv = t >> 6, l = t & 63, l15 = l & 15, q = l >> 4;
  int wm = (wv & 1) * 16, wn = (wv >> 1) * 64;
  f32x4 acc[4];
#pragma unroll
  for (int j = 0; j < 4; j++) acc[j] = (f32x4){0.f,0.f,0.f,0.f};
  const unsigned short* Ag = wo + (size_t)o0 * HID;
  const unsigned short* Bg = AO + ((size_t)b * SEQ + n0) * HID;
  int lrow8 = l >> 3, lcol = l & 7;
  for (int kk = 0; kk < 8; kk++) {
    int k0 = kk * 64;
    __syncthreads();
    {                                      // A: 4 chunks, one per wave
      int row = wv * 8 + lrow8;
      int sg = lcol ^ (row & 7);
      gld16(Ag + (size_t)row * HID + k0 + sg * 8, la + wv * 512);
    }
#pragma unroll
    for (int c0 = 0; c0 < 4; c0++) {       // B: 16 chunks
      int c = wv * 4 + c0;
      int row = c * 8 + lrow8;
      int sg = lcol ^ (row & 7);
      gld16(Bg + (size_t)row * HID + k0 + sg * 8, lb + c * 512);
    }
    __syncthreads();
#pragma unroll
    for (int kh = 0; kh < 2; kh++) {
      bf16x8 af, bfr[4];
      {
        int row = wm + l15;
        af = *(const bf16x8*)(la + row*64 + ((kh*4 + q) ^ (row & 7)) * 8);
      }
#pragma unroll
      for (int nt = 0; nt < 4; nt++) {
        int row = wn + nt*16 + l15;
        bfr[nt] = *(const bf16x8*)(lb + row*64 + ((kh*4 + q) ^ (row & 7)) * 8);
      }
#pragma unroll
      for (int nt = 0; nt < 4; nt++)
        acc[nt] = __builtin_amdgcn_mfma_f32_16x16x32_bf16(af, bfr[nt], acc[nt], 0,0,0);
    }
  }
#pragma unroll
  for (int nt = 0; nt < 4; nt++)
#pragma unroll
    for (int r = 0; r < 4; r++) {
      int o2 = o0 + wm + q*4 + r;
      int n  = n0 + wn + nt*16 + l15;
      out[((size_t)b * DIMC + o2) * SEQ + n] = acc[nt][r] + bias[o2];
    }
}

extern "C" void kernel_launch(void* const* d_in, const int* in_sizes, int n_in,
                              void* d_out, int out_size, void* d_ws, size_t ws_size,
                              hipStream_t stream) {
  const float* x    = (const float*)d_in[0];
  const float* wqkv = (const float*)d_in[1];
  const float* wout = (const float*)d_in[2];
  const float* bout = (const float*)d_in[3];
  float* out = (float*)d_out;
  char* ws = (char*)d_ws;
  unsigned short* wqkv_b = (unsigned short*)(ws);
  unsigned short* wout_b = (unsigned short*)(ws + 786432);
  unsigned short* xT     = (unsigned short*)(ws + 1048576);
  unsigned short* Qs     = (unsigned short*)(ws + 5242880);
  unsigned short* Ks     = (unsigned short*)(ws + 13631488);
  unsigned short* Vt     = (unsigned short*)(ws + 22020096);
  unsigned short* AO     = (unsigned short*)(ws + 30408704);
  prep_kernel<<<1024, 256, 0, stream>>>(x, wqkv, wout, wqkv_b, wout_b, xT);
  qkv_gemm<<<dim3(12, 16, 4), 256, 0, stream>>>(wqkv_b, xT, Qs, Ks, Vt);
  attn_kernel<<<dim3(32, 32), 256, 0, stream>>>(Qs, Ks, Vt, AO);
  out_gemm<<<dim3(8, 16, 4), 256, 0, stream>>>(wout_b, AO, bout, out);
}